// Round 4
// baseline (94.685 us; speedup 1.0000x reference)
//
#include <hip/hip_runtime.h>

#define N_TOT 4096
#define N_HALF 2048
#define DIMS 64
#define BATCH 4
#define TGRID 32             // 4096 / 128 tile rows
#define PAIRS_PER_BATCH 528  // 32*33/2 triangular tiles

typedef __attribute__((ext_vector_type(8))) short short8;
typedef __attribute__((ext_vector_type(4))) float f32x4;

#if __has_builtin(__builtin_amdgcn_exp2f)
#define EXP2F(x) __builtin_amdgcn_exp2f(x)
#else
#define EXP2F(x) exp2f(x)
#endif
#if __has_builtin(__builtin_amdgcn_sqrtf)
#define SQRTF(x) __builtin_amdgcn_sqrtf(x)
#else
#define SQRTF(x) sqrtf(x)
#endif

__device__ __forceinline__ unsigned short f2bf_rne(float f) {
    unsigned int u = __float_as_uint(f);
    unsigned int r = (u + 0x7FFFu + ((u >> 16) & 1u)) >> 16;
    return (unsigned short)r;
}
__device__ __forceinline__ float bf2f(unsigned short h) {
    return __uint_as_float(((unsigned int)h) << 16);
}

// Fused prep: fp32 -> bf16 hi/lo split, row sq-norms, per-batch Ssq (double),
// per-batch column sums. Elementwise-coalesced: 1024 blocks x 256 thr x 4 floats.
// Blocks [0,512) cover x, [512,1024) cover y. 1024 floats per block = 16 rows,
// always within one batch-half.
__global__ __launch_bounds__(256) void prep_kernel(const float* __restrict__ x,
                                                   const float* __restrict__ y,
                                                   unsigned short* __restrict__ hi,
                                                   unsigned short* __restrict__ lo,
                                                   float* __restrict__ sq,
                                                   double* __restrict__ Ssq,
                                                   float* __restrict__ colsum) {
    int g = blockIdx.x;
    int t = threadIdx.x;
    bool isx = g < 512;
    int gg = isx ? g : g - 512;
    int e = (gg << 10) + (t << 2);   // flat float index within x or y
    int b = e >> 17;                 // 2048*64 floats per batch-half
    int rem = e & 131071;
    const float* src = (isx ? x : y) + e;
    size_t dst = (size_t)b * 262144 + (isx ? 0 : 131072) + rem;

    float4 v = *(const float4*)src;
    ushort4 h, l;
    h.x = f2bf_rne(v.x); l.x = f2bf_rne(v.x - bf2f(h.x));
    h.y = f2bf_rne(v.y); l.y = f2bf_rne(v.y - bf2f(h.y));
    h.z = f2bf_rne(v.z); l.z = f2bf_rne(v.z - bf2f(h.z));
    h.w = f2bf_rne(v.w); l.w = f2bf_rne(v.w - bf2f(h.w));
    *(ushort4*)(hi + dst) = h;
    *(ushort4*)(lo + dst) = l;

    // ---- row squared norms (16 consecutive threads own one row) ----
    float p = fmaf(v.x, v.x, fmaf(v.y, v.y, fmaf(v.z, v.z, v.w * v.w)));
    p += __shfl_xor(p, 1);
    p += __shfl_xor(p, 2);
    p += __shfl_xor(p, 4);
    p += __shfl_xor(p, 8);
    int rwi = rem >> 6;  // row within batch-half
    if ((t & 15) == 0)
        sq[b * N_TOT + (isx ? rwi : N_HALF + rwi)] = p;

    // ---- per-batch sum of sq ----
    // After the group reduce, all 16 lanes of a group hold the SAME row sum.
    // xor16 + xor32 cross group boundaries only, so q = r0+r1+r2+r3 exactly
    // (each of the wave's 4 rows counted ONCE — no /16; that was round-3's bug).
    float q = p;
    q += __shfl_xor(q, 16);
    q += __shfl_xor(q, 32);
    __shared__ double wsum[4];
    int wid = t >> 6;
    if ((t & 63) == 0) wsum[wid] = (double)q;

    // ---- column sums: lanes t, t^16, t^32, t^48 share columns ----
    float4 c = v;
    c.x += __shfl_xor(c.x, 16); c.y += __shfl_xor(c.y, 16);
    c.z += __shfl_xor(c.z, 16); c.w += __shfl_xor(c.w, 16);
    c.x += __shfl_xor(c.x, 32); c.y += __shfl_xor(c.y, 32);
    c.z += __shfl_xor(c.z, 32); c.w += __shfl_xor(c.w, 32);
    __shared__ float4 csh[4][16];
    if ((t & 63) < 16) csh[wid][t & 63] = c;
    __syncthreads();
    if (t == 0)
        atomicAdd(Ssq + b, wsum[0] + wsum[1] + wsum[2] + wsum[3]);
    if (t < 16) {
        float4 s0 = csh[0][t], s1 = csh[1][t], s2 = csh[2][t], s3 = csh[3][t];
        float* cb = colsum + b * 64 + t * 4;
        atomicAdd(cb + 0, s0.x + s1.x + s2.x + s3.x);
        atomicAdd(cb + 1, s0.y + s1.y + s2.y + s3.y);
        atomicAdd(cb + 2, s0.z + s1.z + s2.z + s3.z);
        atomicAdd(cb + 3, s0.w + s1.w + s2.w + s3.w);
    }
}

// Main: triangular 128x128 tiles, 4 waves of 64x64, split-bf16 3-pass MFMA,
// inline bandwidth compute, sqrt-chain exp epilogue with wave-uniform weights.
__global__ __launch_bounds__(256) void mmd_mfma(const unsigned short* __restrict__ hi,
                                                const unsigned short* __restrict__ lo,
                                                const float* __restrict__ sq,
                                                const double* __restrict__ Ssq,
                                                const float* __restrict__ colsum,
                                                double* __restrict__ loss) {
    int wg = blockIdx.x;
    int b = wg / PAIRS_PER_BATCH;
    int r = wg % PAIRS_PER_BATCH;
    int ib = 0, cum = 0;
    while (r >= cum + (TGRID - ib)) { cum += TGRID - ib; ++ib; }
    int jb = ib + (r - cum);

    int wid = threadIdx.x >> 6, lane = threadIdx.x & 63;
    int wr = wid >> 1, wc = wid & 1;
    int i_base = ib * 128 + wr * 64;
    int j_base = jb * 128 + wc * 64;

    // ---- inline bandwidth -> k0 = -log2(e)/bw (all lanes identical) ----
    float cv = colsum[b * 64 + lane];
    double s2 = (double)cv * (double)cv;
#pragma unroll
    for (int o = 32; o > 0; o >>= 1) s2 += __shfl_xor(s2, o);
    double sumL2 = 2.0 * (double)N_TOT * Ssq[b] - 2.0 * s2;
    double bw = sumL2 / ((double)N_TOT * (double)N_TOT - (double)N_TOT);
    bw *= 0.25;  // / KERNEL_MUL^(KERNEL_NUM//2)
    float k0 = (float)(-1.4426950408889634 / bw);

    bool skip = (i_base > j_base);  // strictly-lower wave of a diag block
    bool diag = (i_base == j_base);
    float wsign = ((i_base < N_HALF) == (j_base < N_HALF)) ? 1.f : -1.f;

    double acc_d = 0.0;
    if (!skip) {
        const unsigned short* Hb = hi + (size_t)b * 262144;
        const unsigned short* Lb = lo + (size_t)b * 262144;
        int lrow = lane & 15;
        int kblk = (lane >> 4) * 8;

        f32x4 acc[4][4];
#pragma unroll
        for (int mf = 0; mf < 4; ++mf)
#pragma unroll
            for (int nf = 0; nf < 4; ++nf)
                acc[mf][nf] = (f32x4){0.f, 0.f, 0.f, 0.f};

#pragma unroll
        for (int ks = 0; ks < 2; ++ks) {
            short8 ah[4], al[4], bh[4], bl[4];
            int ko = ks * 32 + kblk;
#pragma unroll
            for (int f = 0; f < 4; ++f) {
                size_t ra = (size_t)(i_base + f * 16 + lrow) * DIMS + ko;
                size_t rb = (size_t)(j_base + f * 16 + lrow) * DIMS + ko;
                ah[f] = *(const short8*)(Hb + ra);
                al[f] = *(const short8*)(Lb + ra);
                bh[f] = *(const short8*)(Hb + rb);
                bl[f] = *(const short8*)(Lb + rb);
            }
#pragma unroll
            for (int mf = 0; mf < 4; ++mf)
#pragma unroll
                for (int nf = 0; nf < 4; ++nf) {
                    acc[mf][nf] = __builtin_amdgcn_mfma_f32_16x16x32_bf16(ah[mf], bh[nf], acc[mf][nf], 0, 0, 0);
                    acc[mf][nf] = __builtin_amdgcn_mfma_f32_16x16x32_bf16(ah[mf], bl[nf], acc[mf][nf], 0, 0, 0);
                    acc[mf][nf] = __builtin_amdgcn_mfma_f32_16x16x32_bf16(al[mf], bh[nf], acc[mf][nf], 0, 0, 0);
                }
        }

        const float* sqb = sq + b * N_TOT;
        int rquad = (lane >> 4) * 4;  // C layout: row = (lane>>4)*4 + reg
        float sqi[4][4], sqjv[4];
#pragma unroll
        for (int mf = 0; mf < 4; ++mf)
#pragma unroll
            for (int rg = 0; rg < 4; ++rg)
                sqi[mf][rg] = sqb[i_base + mf * 16 + rquad + rg];
#pragma unroll
        for (int nf = 0; nf < 4; ++nf)
            sqjv[nf] = sqb[j_base + nf * 16 + lrow];

        float eacc = 0.f;
#pragma unroll
        for (int mf = 0; mf < 4; ++mf)
#pragma unroll
            for (int nf = 0; nf < 4; ++nf) {
#pragma unroll
                for (int rg = 0; rg < 4; ++rg) {
                    float s = sqi[mf][rg] + sqjv[nf];
                    float L2 = fmaf(-2.f, acc[mf][nf][rg], s);
                    float e0 = EXP2F(L2 * k0);
                    float e1 = SQRTF(e0);
                    float e2 = SQRTF(e1);
                    float e3 = SQRTF(e2);
                    float e4 = SQRTF(e3);
                    float es = ((e0 + e1) + (e2 + e3)) + e4;
                    if (diag) {
                        int i = i_base + mf * 16 + rquad + rg;
                        int j = j_base + nf * 16 + lrow;
                        float w = (j > i) ? 2.f : ((j == i) ? 1.f : 0.f);
                        eacc = fmaf(w, es, eacc);
                    } else {
                        eacc += es;
                    }
                }
            }
        float scale = diag ? wsign : 2.f * wsign;
        acc_d = (double)(eacc * scale);
    }

#pragma unroll
    for (int o = 32; o > 0; o >>= 1) acc_d += __shfl_down(acc_d, o);
    __shared__ double wred[4];
    if ((threadIdx.x & 63) == 0) wred[wid] = acc_d;
    __syncthreads();
    if (threadIdx.x == 0)
        atomicAdd(loss + b, wred[0] + wred[1] + wred[2] + wred[3]);
}

__global__ void finalize_kernel(const double* __restrict__ loss,
                                float* __restrict__ out) {
    int t = threadIdx.x;
    if (t < BATCH)
        out[t] = (float)(loss[t] / ((double)N_HALF * (double)N_HALF));
}

extern "C" void kernel_launch(void* const* d_in, const int* in_sizes, int n_in,
                              void* d_out, int out_size, void* d_ws, size_t ws_size,
                              hipStream_t stream) {
    const float* x = (const float*)d_in[0];
    const float* y = (const float*)d_in[1];
    float* out = (float*)d_out;
    char* ws = (char*)d_ws;

    double* Ssq    = (double*)ws;                 // [0, 32)
    double* loss   = (double*)(ws + 64);          // [64, 96)
    float*  colsum = (float*)(ws + 128);          // [128, 1152)
    float*  sq     = (float*)(ws + 4096);         // [4096, 69632)
    unsigned short* tot_hi = (unsigned short*)(ws + 69632);              // 2 MB
    unsigned short* tot_lo = (unsigned short*)(ws + 69632 + 2097152);    // 2 MB

    hipMemsetAsync(ws, 0, 1152, stream);

    prep_kernel<<<1024, 256, 0, stream>>>(x, y, tot_hi, tot_lo, sq, Ssq, colsum);
    mmd_mfma<<<BATCH * PAIRS_PER_BATCH, 256, 0, stream>>>(tot_hi, tot_lo, sq, Ssq, colsum, loss);
    finalize_kernel<<<1, 64, 0, stream>>>(loss, out);
}